// Round 4
// baseline (180.007 us; speedup 1.0000x reference)
//
#include <hip/hip_runtime.h>

// VectorQuantizer: N=65536 rows, D=256, K=1024 codes, fp32 in/out.
// argmin_k ||x-e_k||^2 == argmax_k (x.e_k - 0.5*||e_k||^2).
// R4: barrier-free main loop. vq_prep packs the fp16 codebook in MFMA
// fragment order (ehp[h][c][s][lane] 16B); vq_main loads A-fragments
// directly global->VGPR (coalesced dwordx4, L2-resident 512 KB) with
// ping-pong 4-frag buffers -> no LDS, no __syncthreads in the 16-chunk
// loop; waves free-run and the L2/VALU/MFMA pipes overlap across waves.
// Blocks: 256 threads / 4 waves (p-group x code-half) / 64 rows; LDS only
// for the one-shot coalesced x prologue (32 KB swizzled stage) + epilogue
// merge. Numerics identical to verified kernels: single fp16 term
// (|err|<~0.02), 10-bit code-in-mantissa packing (quant <=0.03), exact
// fp32 rescue when approx top-2 margin <= 0.25.

#define K_EMB  1024
#define D_DIM  256
#define N_ROWS 65536

typedef unsigned int u32;
typedef unsigned long long u64;
typedef __attribute__((ext_vector_type(8)))  _Float16 f16x8;
typedef __attribute__((ext_vector_type(4)))  _Float16 f16x4;
typedef __attribute__((ext_vector_type(16))) float    f32x16;

__device__ __forceinline__ u32 f32_sortable(float f) {
    u32 u = __float_as_uint(f);
    return u ^ ((u32)((int)u >> 31) | 0x80000000u);
}
__device__ __forceinline__ float f32_unsort(u32 u) {
    u32 v = (u & 0x80000000u) ? (u ^ 0x80000000u) : ~u;
    return __uint_as_float(v);
}

// ---- prep: emb fp32 -> packed fp16 frags; cn2[code]={-cnh,-cnl,0..};
// ---- exact fp32 cnorm.
// Packed layout: halfs offset = (((h*16+c)*16+s)*64 + kh*32 + m)*8 + j
//   for code = h*512 + c*32 + m, dim = s*16 + kh*8 + j.
__global__ void vq_prep(const float* __restrict__ emb,
                        _Float16* __restrict__ ehp,
                        _Float16* __restrict__ cn2,
                        float* __restrict__ cnormf) {
    int gid = blockIdx.x * 256 + threadIdx.x;
    int code = gid >> 6, lane = gid & 63;
    float4 v = ((const float4*)(emb + (size_t)code * D_DIM))[lane];
    f16x4 hv = {(_Float16)v.x, (_Float16)v.y, (_Float16)v.z, (_Float16)v.w};
    {
        int h = code >> 9, c = (code >> 5) & 15, m = code & 31;
        int s = lane >> 2, kh = (lane >> 1) & 1, jlo = lane & 1;
        size_t halfs = ((((size_t)(h * 16 + c) * 16 + s) * 64) + kh * 32 + m) * 8
                     + jlo * 4;
        *(f16x4*)(ehp + halfs) = hv;
    }
    float s = v.x * v.x + v.y * v.y + v.z * v.z + v.w * v.w;
    #pragma unroll
    for (int off = 32; off > 0; off >>= 1) s += __shfl_down(s, off, 64);
    if (lane == 0) {
        float cn = 0.5f * s;
        cnormf[code] = cn;
        _Float16 ch = (_Float16)cn;
        _Float16 cl = (_Float16)(cn - (float)ch);
        f16x8 e = {};
        e[0] = (_Float16)(-(float)ch);
        e[1] = (_Float16)(-(float)cl);
        ((f16x8*)cn2)[code] = e;
    }
}

// ---- fused main: barrier-free GEMM + top3 + merge + rescue + gather ----
__global__ __launch_bounds__(256, 4) void vq_main(
    const float* __restrict__ x, const float* __restrict__ emb,
    const _Float16* __restrict__ ehp, const _Float16* __restrict__ cn2,
    const float* __restrict__ cnormf,
    float* __restrict__ outq, float* __restrict__ outi)
{
    __shared__ _Float16 XS[16384];    // 32 KB one-shot x staging
    __shared__ u32 xchg[2][64][3];    // [code-half][local row][rank]
    __shared__ int winners[64];

    const int t = threadIdx.x, w = t >> 6, lane = t & 63;
    const int m = lane & 31, kh = lane >> 5;
    const int p = w >> 1;                 // row-group 0..1 (32 rows each)
    const int h = w & 1;                  // code half: codes h*512..+512
    const int blkrow = blockIdx.x * 64;
    const int kh4 = kh * 4;

    // ---- coalesced x prologue through XS (single 64-row pass) ----
    // write: [row][dim] fp16, 512 B/row, byte ^= (row&7)<<4 swizzle.
    f16x8 bh[16];
    {
        char* xb = (char*)XS;
        #pragma unroll
        for (int i = 0; i < 16; i++) {
            int row = i * 4 + w;          // 0..63, whole row per wave-instr
            float4 v = *(const float4*)(
                x + (size_t)(blkrow + row) * D_DIM + lane * 4);
            f16x4 hv = {(_Float16)v.x, (_Float16)v.y,
                        (_Float16)v.z, (_Float16)v.w};
            u32 byte = (u32)(row * 512 + lane * 8) ^ ((u32)(row & 7) << 4);
            *(f16x4*)(xb + byte) = hv;
        }
        __syncthreads();
        int lr = p * 32 + m;
        #pragma unroll
        for (int s = 0; s < 16; s++) {
            u32 byte = (u32)(lr * 512 + s * 32 + kh * 16)
                     ^ ((u32)(lr & 7) << 4);
            bh[s] = *(const f16x8*)(xb + byte);
        }
    }
    f16x8 xe = {};
    if (kh == 0) { xe[0] = (_Float16)1.0f; xe[1] = (_Float16)1.0f; }

    u32 A1 = 0, A2 = 0, A3 = 0;

    auto t3 = [](u32& c1, u32& c2, u32& c3, u32 pv) {
        u32 u2 = c1 < pv ? c1 : pv;       // min(c1,pv)
        u32 u3 = c2 < pv ? c2 : pv;       // min(c2,pv)
        c1 = c1 > pv ? c1 : pv;
        c2 = u2 > c2 ? u2 : c2;
        c3 = u3 > c3 ? u3 : c3;
    };

    // ---- barrier-free main loop: direct global->VGPR A-fragments ----
    // frag(c,s) for this lane at ehp_bytes + ((h*256 + c*16 + s)*64 + lane)*16.
    // pc advances by 4096 per 4-frag group; the final group of chunk 15
    // over-reads 4 KB past this h-half (lands in h=1 region / cn2, both
    // inside the workspace; values never used).
    const char* pc = (const char*)ehp + ((size_t)h * 16384 + lane) * 16;
    const f16x8* cn2f = (const f16x8*)cn2 + (size_t)h * 512 + m;

    f16x8 f0[4], f1[4];
    #define LD4(B) { (B)[0] = *(const f16x8*)(pc); \
                     (B)[1] = *(const f16x8*)(pc + 1024); \
                     (B)[2] = *(const f16x8*)(pc + 2048); \
                     (B)[3] = *(const f16x8*)(pc + 3072); pc += 4096; }
    #define MF4(B, S) { \
        a = __builtin_amdgcn_mfma_f32_32x32x16_f16((B)[0], bh[(S)],     a, 0, 0, 0); \
        a = __builtin_amdgcn_mfma_f32_32x32x16_f16((B)[1], bh[(S) + 1], a, 0, 0, 0); \
        a = __builtin_amdgcn_mfma_f32_32x32x16_f16((B)[2], bh[(S) + 2], a, 0, 0, 0); \
        a = __builtin_amdgcn_mfma_f32_32x32x16_f16((B)[3], bh[(S) + 3], a, 0, 0, 0); }

    LD4(f0);
    for (int c = 0; c < 16; ++c) {
        f32x16 a = {};
        f16x8 e = cn2f[c * 32];
        LD4(f1);
        MF4(f0, 0);
        LD4(f0);
        MF4(f1, 4);
        LD4(f1);
        MF4(f0, 8);
        LD4(f0);                 // next chunk's s=0..3 (benign tail read)
        MF4(f1, 12);
        a = __builtin_amdgcn_mfma_f32_32x32x16_f16(e, xe, a, 0, 0, 0);
        const u32 sbase = (u32)(h * 512 + c * 32) + kh4;
        #pragma unroll
        for (int r = 0; r < 16; r++) {
            u32 code = sbase + (r & 3) + 8 * (r >> 2);
            u32 pk = (f32_sortable(a[r]) & 0xFFFFFC00u) | code;
            t3(A1, A2, A3, pk);
        }
    }
    #undef LD4
    #undef MF4

    // merge the two kh-halves of each row (partner lane = lane ^ 32)
    {
        u32 q1 = (u32)__shfl_xor((int)A1, 32, 64);
        u32 q2 = (u32)__shfl_xor((int)A2, 32, 64);
        u32 q3 = (u32)__shfl_xor((int)A3, 32, 64);
        t3(A1, A2, A3, q1); t3(A1, A2, A3, q2); t3(A1, A2, A3, q3);
    }

    // cross-wave (code-half) exchange of per-row top3
    if (kh == 0) {
        int ra = p * 32 + m;
        xchg[h][ra][0] = A1; xchg[h][ra][1] = A2; xchg[h][ra][2] = A3;
    }
    __syncthreads();

    // epilogue: each wave owns 16 rows (local rows w*16 .. w*16+16)
    const int lr = w * 16 + (lane & 15);
    u32 c1 = 0, c2 = 0, c3 = 0;
    #pragma unroll
    for (int hh = 0; hh < 2; hh++) {
        t3(c1, c2, c3, xchg[hh][lr][0]);
        t3(c1, c2, c3, xchg[hh][lr][1]);
        t3(c1, c2, c3, xchg[hh][lr][2]);
    }

    // rescue selection: exact fp32 re-eval when approx margin <= 0.25
    float s1f = f32_unsort(c1), s2f = f32_unsort(c2), s3f = f32_unsort(c3);
    u32 i1 = c1 & 1023u, i2 = c2 & 1023u, i3 = c3 & 1023u;
    const bool act = lane < 16;
    bool need = (s1f - s2f) <= 0.25f;
    if (act && !need) winners[lr] = (int)i1;
    u64 mask = __ballot(act && need);
    while (mask) {
        int r = __ffsll((unsigned long long)mask) - 1;
        mask &= mask - 1;
        int row = blkrow + w * 16 + r;
        u32 d1 = (u32)__shfl((int)i1, r, 64);
        u32 d2 = (u32)__shfl((int)i2, r, 64);
        u32 d3 = (u32)__shfl((int)i3, r, 64);
        float g3 = __shfl(s1f - s3f, r, 64);
        int ncand = (g3 <= 0.25f) ? 3 : 2;
        float4 xv = ((const float4*)(x + (size_t)row * D_DIM))[lane];
        float bs = -3.0e38f; int bi = 0x7fffffff;
        u32 cand[3] = {d1, d2, d3};
        for (int q = 0; q < ncand; q++) {
            int ccd = (int)cand[q];
            float4 ev = ((const float4*)(emb + (size_t)ccd * D_DIM))[lane];
            float d = xv.x * ev.x + xv.y * ev.y + xv.z * ev.z + xv.w * ev.w;
            #pragma unroll
            for (int dd = 1; dd < 64; dd <<= 1) d += __shfl_xor(d, dd, 64);
            float sc = d - cnormf[ccd];
            if (sc > bs || (sc == bs && ccd < bi)) { bs = sc; bi = ccd; }
        }
        if (lane == 0) winners[w * 16 + r] = bi;
    }

    // index write + gather (winners slots are wave-private; no barrier needed)
    if (act) outi[blkrow + lr] = (float)winners[lr];
    #pragma unroll 8
    for (int r = 0; r < 16; r++) {
        int idx = winners[w * 16 + r];
        int row = blkrow + w * 16 + r;
        float4 qv = ((const float4*)(emb + (size_t)idx * D_DIM))[lane];
        ((float4*)(outq + (size_t)row * D_DIM))[lane] = qv;
    }
}

extern "C" void kernel_launch(void* const* d_in, const int* in_sizes, int n_in,
                              void* d_out, int out_size, void* d_ws, size_t ws_size,
                              hipStream_t stream) {
    const float* x   = (const float*)d_in[0];
    const float* emb = (const float*)d_in[1];
    float* outq = (float*)d_out;
    float* outi = outq + (size_t)N_ROWS * D_DIM;

    _Float16* ehp = (_Float16*)d_ws;                              // 512 KB packed
    _Float16* cn2 = ehp + (size_t)K_EMB * D_DIM;                  // 16 KB
    float* cnormf = (float*)(cn2 + (size_t)K_EMB * 8);            // 4 KB

    vq_prep<<<K_EMB / 4, 256, 0, stream>>>(emb, ehp, cn2, cnormf);
    vq_main<<<N_ROWS / 64, 256, 0, stream>>>(x, emb, ehp, cn2, cnormf,
                                             outq, outi);
}

// Round 5
// 155.133 us; speedup vs baseline: 1.1603x; 1.1603x over previous
//
#include <hip/hip_runtime.h>

// VectorQuantizer: N=65536 rows, D=256, K=1024 codes, fp32 in/out.
// argmin_k ||x-e_k||^2 == argmax_k (x.e_k - 0.5*||e_k||^2).
// R5 = R3 structure (512-thread blocks, 8 waves = 4 row-groups x 2
// code-halves, LDS double-buffered GLDS codebook staging) + counted-vmcnt
// pipeline (T3/T4): per chunk, two RAW s_barriers (WAR-retire + RAW-
// publish) with s_waitcnt vmcnt(4) so the next tile's 4 GLDS stay in
// flight across the whole chunk compute -- no vmcnt(0) drain in the loop
// (that drain was R3's ~3x-over-floor stall). sched_barrier(0) pins keep
// compiler lgkmcnt waits + MFMA consumers above each barrier (rule #18).
// s_setprio(1) wraps the MFMA cluster (T5). cnorm pairs live in a 4 KB
// LDS array (ds_read, lgkm domain) so loop VMEM = exactly 4 GLDS/chunk.
// R4 lesson: direct global->VGPR A-frags need 512 B/cyc/CU; L1 path gives
// ~64 -> codebook must stream through LDS.
// Numerics identical to verified kernels: single fp16 term (|err|<~0.02),
// 10-bit code-in-mantissa packing (quant <=0.03), exact fp32 rescue when
// approx top-2 margin <= 0.25.

#define K_EMB  1024
#define D_DIM  256
#define N_ROWS 65536

typedef unsigned int u32;
typedef unsigned long long u64;
typedef __attribute__((ext_vector_type(8)))  _Float16 f16x8;
typedef __attribute__((ext_vector_type(4)))  _Float16 f16x4;
typedef __attribute__((ext_vector_type(16))) float    f32x16;

__device__ __forceinline__ u32 f32_sortable(float f) {
    u32 u = __float_as_uint(f);
    return u ^ ((u32)((int)u >> 31) | 0x80000000u);
}
__device__ __forceinline__ float f32_unsort(u32 u) {
    u32 v = (u & 0x80000000u) ? (u ^ 0x80000000u) : ~u;
    return __uint_as_float(v);
}

#define GLDS(gp, lp) __builtin_amdgcn_global_load_lds( \
    (const __attribute__((address_space(1))) void*)(gp), \
    (__attribute__((address_space(3))) void*)(lp), 16, 0, 0)

// ---- prep: emb fp32 -> fp16 (linear [code][dim]); cn2c[code] = packed
// ---- {-cnh,-cnl} fp16 pair (u32); exact fp32 cnorm ----
__global__ void vq_prep(const float* __restrict__ emb,
                        _Float16* __restrict__ ehi,
                        u32* __restrict__ cn2c,
                        float* __restrict__ cnormf) {
    int gid = blockIdx.x * 256 + threadIdx.x;
    int code = gid >> 6, lane = gid & 63;
    float4 v = ((const float4*)(emb + (size_t)code * D_DIM))[lane];
    f16x4 hv = {(_Float16)v.x, (_Float16)v.y, (_Float16)v.z, (_Float16)v.w};
    ((f16x4*)(ehi + (size_t)code * D_DIM))[lane] = hv;
    float s = v.x * v.x + v.y * v.y + v.z * v.z + v.w * v.w;
    #pragma unroll
    for (int off = 32; off > 0; off >>= 1) s += __shfl_down(s, off, 64);
    if (lane == 0) {
        float cn = 0.5f * s;
        cnormf[code] = cn;
        _Float16 ch = (_Float16)cn;
        _Float16 cl = (_Float16)(cn - (float)ch);
        union { _Float16 hh[2]; u32 uu; } pk;
        pk.hh[0] = (_Float16)(-(float)ch);
        pk.hh[1] = (_Float16)(-(float)cl);
        cn2c[code] = pk.uu;
    }
}

// ---- fused main: GEMM + top3 + cross-wave merge + rescue + gather ----
__global__ __launch_bounds__(512, 4) void vq_main(
    const float* __restrict__ x, const float* __restrict__ emb,
    const _Float16* __restrict__ eh, const u32* __restrict__ cn2c,
    const float* __restrict__ cnormf,
    float* __restrict__ outq, float* __restrict__ outi)
{
    // T[parity][code-half][s 0..15][kh][code 0..31][8 halfs]: 2 x 32 KB
    __shared__ _Float16 T[2][2][8192];
    __shared__ u32 CNs[1024];         // packed {-cnh,-cnl} per code, 4 KB
    __shared__ u32 xchg[2][128][3];   // [code-half][local row][rank]
    __shared__ int winners[128];

    const int t = threadIdx.x, w = t >> 6, lane = t & 63;
    const int m = lane & 31, kh = lane >> 5;
    const int p = w >> 1;                 // row-group 0..3 (32 rows each)
    const int h = w & 1;                  // code half: codes h*512..+512
    const int blkrow = blockIdx.x * 128;
    const int kh4 = kh * 4;

    // stage chunk c (32 codes per half) into T[c&1]; wave w covers half h,
    // dim-regions r = p*4 + [0..4)  -> exactly 4 GLDS per wave per chunk.
    auto stage = [&](int c) {
        _Float16* dstb = &T[c & 1][h][0];
        const _Float16* srcb = eh + (size_t)(h * 512 + c * 32 + m) * D_DIM + kh * 8;
        #pragma unroll
        for (int i = 0; i < 4; i++) {
            int r = p * 4 + i;
            GLDS(srcb + r * 16, dstb + r * 512);
        }
    };

    stage(0);   // first codebook tile in flight during the x prologue

    // cnorm pairs -> LDS (one-time; visible after first __syncthreads)
    CNs[t] = cn2c[t];
    CNs[t + 512] = cn2c[t + 512];

    // ---- coalesced x prologue through T[1] (two 64-row passes) ----
    // write: [row][dim] fp16, 512 B/row, byte ^= (row&7)<<4 swizzle.
    // read:  lane(m,kh) frag s = halfs [lr][s*16+kh*8..+8) -> ds_read_b128.
    f16x8 bh[16];
    {
        char* xb = (char*)&T[1][0][0];    // 32 KB staging region
        #pragma unroll
        for (int k = 0; k < 2; k++) {
            #pragma unroll
            for (int i = 0; i < 8; i++) {
                int row = i * 8 + w;       // 0..63, whole row per wave-instr
                float4 v = *(const float4*)(
                    x + (size_t)(blkrow + k * 64 + row) * D_DIM + lane * 4);
                f16x4 hv = {(_Float16)v.x, (_Float16)v.y,
                            (_Float16)v.z, (_Float16)v.w};
                u32 byte = (u32)(row * 512 + lane * 8) ^ ((u32)(row & 7) << 4);
                *(f16x4*)(xb + byte) = hv;
            }
            __syncthreads();
            if ((p >> 1) == k) {
                int lr = (p & 1) * 32 + m;
                #pragma unroll
                for (int s = 0; s < 16; s++) {
                    u32 byte = (u32)(lr * 512 + s * 32 + kh * 16)
                             ^ ((u32)(lr & 7) << 4);
                    bh[s] = *(const f16x8*)(xb + byte);
                }
            }
            __syncthreads();
        }
    }
    f16x8 xe = {};
    if (kh == 0) { xe[0] = (_Float16)1.0f; xe[1] = (_Float16)1.0f; }

    u32 A1 = 0, A2 = 0, A3 = 0;

    auto t3 = [](u32& c1, u32& c2, u32& c3, u32 pv) {
        u32 u2 = c1 < pv ? c1 : pv;       // min(c1,pv)
        u32 u3 = c2 < pv ? c2 : pv;       // min(c2,pv)
        c1 = c1 > pv ? c1 : pv;
        c2 = u2 > c2 ? u2 : c2;
        c3 = u3 > c3 ? u3 : c3;
    };

    // ---- main loop: 16 chunks, counted-vmcnt pipeline, no drains ----
    // iter c: [SB; s_barrier]  WAR: all waves done reading T[(c+1)&1] (iter c-1)
    //         stage(c+1); vmcnt(4)   c's tile retired, c+1's 4 loads in flight
    //         [SB; s_barrier]  RAW: T[c&1] visible to all waves
    //         compute chunk c (setprio(1) around MFMA cluster), top3
    for (int c = 0; c < 16; ++c) {
        __builtin_amdgcn_sched_barrier(0);
        __builtin_amdgcn_s_barrier();
        if (c < 15) {
            stage(c + 1);
            asm volatile("s_waitcnt vmcnt(4)" ::: "memory");
        } else {
            asm volatile("s_waitcnt vmcnt(0)" ::: "memory");
        }
        __builtin_amdgcn_sched_barrier(0);
        __builtin_amdgcn_s_barrier();

        const f16x8* Af = (const f16x8*)&T[c & 1][h][0];
        union { u32 uu; _Float16 hh[2]; } uv;
        uv.uu = CNs[h * 512 + c * 32 + m];
        f16x8 e = {};
        e[0] = uv.hh[0]; e[1] = uv.hh[1];
        f32x16 a = {};
        __builtin_amdgcn_s_setprio(1);
        #pragma unroll
        for (int s = 0; s < 16; s++) {
            f16x8 fa = Af[(2 * s + kh) * 32 + m];
            a = __builtin_amdgcn_mfma_f32_32x32x16_f16(fa, bh[s], a, 0, 0, 0);
        }
        a = __builtin_amdgcn_mfma_f32_32x32x16_f16(e, xe, a, 0, 0, 0);
        __builtin_amdgcn_s_setprio(0);

        const u32 sbase = (u32)(h * 512 + c * 32) + kh4;
        #pragma unroll
        for (int r = 0; r < 16; r++) {
            u32 code = sbase + (r & 3) + 8 * (r >> 2);
            u32 pk = (f32_sortable(a[r]) & 0xFFFFFC00u) | code;
            t3(A1, A2, A3, pk);
        }
    }

    // merge the two kh-halves of each row (partner lane = lane ^ 32)
    {
        u32 q1 = (u32)__shfl_xor((int)A1, 32, 64);
        u32 q2 = (u32)__shfl_xor((int)A2, 32, 64);
        u32 q3 = (u32)__shfl_xor((int)A3, 32, 64);
        t3(A1, A2, A3, q1); t3(A1, A2, A3, q2); t3(A1, A2, A3, q3);
    }

    // cross-wave (code-half) exchange of per-row top3
    if (kh == 0) {
        int ra = p * 32 + m;
        xchg[h][ra][0] = A1; xchg[h][ra][1] = A2; xchg[h][ra][2] = A3;
    }
    __syncthreads();

    // epilogue: each wave owns 16 rows (local rows w*16 .. w*16+16)
    const int lr = w * 16 + (lane & 15);
    u32 c1 = 0, c2 = 0, c3 = 0;
    #pragma unroll
    for (int hh = 0; hh < 2; hh++) {
        t3(c1, c2, c3, xchg[hh][lr][0]);
        t3(c1, c2, c3, xchg[hh][lr][1]);
        t3(c1, c2, c3, xchg[hh][lr][2]);
    }

    // rescue selection: exact fp32 re-eval when approx margin <= 0.25
    float s1f = f32_unsort(c1), s2f = f32_unsort(c2), s3f = f32_unsort(c3);
    u32 i1 = c1 & 1023u, i2 = c2 & 1023u, i3 = c3 & 1023u;
    const bool act = lane < 16;
    bool need = (s1f - s2f) <= 0.25f;
    if (act && !need) winners[lr] = (int)i1;
    u64 mask = __ballot(act && need);
    while (mask) {
        int r = __ffsll((unsigned long long)mask) - 1;
        mask &= mask - 1;
        int row = blkrow + w * 16 + r;
        u32 d1 = (u32)__shfl((int)i1, r, 64);
        u32 d2 = (u32)__shfl((int)i2, r, 64);
        u32 d3 = (u32)__shfl((int)i3, r, 64);
        float g3 = __shfl(s1f - s3f, r, 64);
        int ncand = (g3 <= 0.25f) ? 3 : 2;
        float4 xv = ((const float4*)(x + (size_t)row * D_DIM))[lane];
        float bs = -3.0e38f; int bi = 0x7fffffff;
        u32 cand[3] = {d1, d2, d3};
        for (int q = 0; q < ncand; q++) {
            int ccd = (int)cand[q];
            float4 ev = ((const float4*)(emb + (size_t)ccd * D_DIM))[lane];
            float d = xv.x * ev.x + xv.y * ev.y + xv.z * ev.z + xv.w * ev.w;
            #pragma unroll
            for (int dd = 1; dd < 64; dd <<= 1) d += __shfl_xor(d, dd, 64);
            float sc = d - cnormf[ccd];
            if (sc > bs || (sc == bs && ccd < bi)) { bs = sc; bi = ccd; }
        }
        if (lane == 0) winners[w * 16 + r] = bi;
    }

    // index write + gather (winners slots are wave-private; no barrier needed)
    if (act) outi[blkrow + lr] = (float)winners[lr];
    #pragma unroll 8
    for (int r = 0; r < 16; r++) {
        int idx = winners[w * 16 + r];
        int row = blkrow + w * 16 + r;
        float4 qv = ((const float4*)(emb + (size_t)idx * D_DIM))[lane];
        ((float4*)(outq + (size_t)row * D_DIM))[lane] = qv;
    }
}

extern "C" void kernel_launch(void* const* d_in, const int* in_sizes, int n_in,
                              void* d_out, int out_size, void* d_ws, size_t ws_size,
                              hipStream_t stream) {
    const float* x   = (const float*)d_in[0];
    const float* emb = (const float*)d_in[1];
    float* outq = (float*)d_out;
    float* outi = outq + (size_t)N_ROWS * D_DIM;

    _Float16* ehi = (_Float16*)d_ws;                              // 512 KB
    u32* cn2c = (u32*)(ehi + (size_t)K_EMB * D_DIM);              // 4 KB
    float* cnormf = (float*)(cn2c + K_EMB);                       // 4 KB

    vq_prep<<<K_EMB / 4, 256, 0, stream>>>(emb, ehi, cn2c, cnormf);
    vq_main<<<N_ROWS / 128, 512, 0, stream>>>(x, emb, ehi, cn2c, cnormf,
                                              outq, outi);
}